// Round 1
// baseline (421.775 us; speedup 1.0000x reference)
//
#include <hip/hip_runtime.h>
#include <hip/hip_bf16.h>
#include <stdint.h>

// Attention layer, MI355X. RoPE is a no-op, mask is exactly causal.
// cvt fp32->bf16 (scale*log2e folded into wq); fused QKV GEMM (V written
// transposed) now a counted-vmcnt pipelined 128x384 kernel (T3+T4+T5+T1);
// causal flash attention (S^T trick, no-max exp2 softmax); out-proj GEMM
// kept at the R4 128x128 single-buffer structure.

namespace {

constexpr int kB = 2;
constexpr int kS = 2048;
constexpr int kD = 2048;
constexpr int kH = 16;
constexpr int kHD = 128;
constexpr int kM = kB * kS;  // 4096 token rows

typedef __attribute__((ext_vector_type(8))) __bf16 bf16x8;
typedef __attribute__((ext_vector_type(4))) float f32x4;

__device__ __forceinline__ unsigned short f2bf(float x) {
  uint32_t u = __float_as_uint(x);
  u += 0x7fffu + ((u >> 16) & 1u);
  return (unsigned short)(u >> 16);
}

__device__ __forceinline__ void gld_lds16(const void* g, void* l) {
  __builtin_amdgcn_global_load_lds((__attribute__((address_space(1))) void*)g,
                                   (__attribute__((address_space(3))) void*)l,
                                   16, 0, 0);
}

// ---------------- all fp32 -> bf16 casts, one dispatch ----------------
__global__ void cvt_all(const float* __restrict__ x, const float* __restrict__ wq,
                        const float* __restrict__ wk, const float* __restrict__ wv,
                        const float* __restrict__ wo, unsigned short* __restrict__ xb,
                        unsigned short* __restrict__ wqkv) {
  constexpr int n4 = kD * kD / 4;
  const int i = blockIdx.x * blockDim.x + threadIdx.x;
  const int y = blockIdx.y;
  const float* src;
  unsigned short* dst;
  float s = 1.0f;
  if (y < 2) {
    src = x + (size_t)y * n4 * 4;
    dst = xb + (size_t)y * n4 * 4;
  } else {
    src = (y == 2) ? wq : (y == 3) ? wk : (y == 4) ? wv : wo;
    dst = wqkv + (size_t)(y - 2) * n4 * 4;
    if (y == 2) s = 0.08838834764831845f * 1.44269504088896340736f;
  }
  float4 v = ((const float4*)src)[i];
  ushort4 o;
  o.x = f2bf(v.x * s); o.y = f2bf(v.y * s); o.z = f2bf(v.z * s); o.w = f2bf(v.w * s);
  ((ushort4*)dst)[i] = o;
}

// ---------------- QKV GEMM: 128x384 tile, counted-vmcnt pipeline ----------
// 8 waves (2M x 4N), per-wave 64x96 output (4x6 16x16 frags). K-tiles of 64
// split into K-halves of 32 -> 4 LDS regions (2 buf x 2 half), region of
// phase g is R(g) with period 4. Phase g: ds_read frags for half g (landing
// guaranteed by prev phase's vmcnt(8)+barrier); issue 4 global_load_lds for
// half g+3 (its region was last read at phase g-1 -> async write race-free);
// 24 MFMA under setprio; s_waitcnt vmcnt(8) (2 half-stages in flight, never
// drained) + raw s_barrier + asm memory fences. Epilogue drains 8->4->0.
// Grid: 512 blocks = 2 balanced rounds at 1 block/CU (128 KiB LDS); flat
// blockIdx with bijective XCD swizzle (512 % 8 == 0), N fastest per XCD.
// Accumulation order over k identical to the old kernel (bit-identical C).

#define QKV_STAGE(T2, Q2)                                                      \
  {                                                                            \
    const int kof = (T2) * 64 + (Q2) * 32;                                     \
    const int sbuf = (T2) & 1;                                                 \
    gld_lds16(gA + kof, &Asm[sbuf][Q2][0] + wave * 512);                       \
    unsigned short* lb = &Bsm[sbuf][Q2][0] + wave * 512;                       \
    const unsigned short* gw = gW + kof;                                       \
    gld_lds16(gw, lb);                                                         \
    gld_lds16(gw + (size_t)128 * 2048, lb + 4096);                             \
    gld_lds16(gw + (size_t)256 * 2048, lb + 8192);                             \
  }

#define QKV_SYNC(VMS)                                                          \
  asm volatile("s_waitcnt vmcnt(" VMS ")" ::: "memory");                       \
  __builtin_amdgcn_s_barrier();                                                \
  asm volatile("" ::: "memory");

#define QKV_PHASE(BUF, Q, DOSTAGE, T2, Q2)                                     \
  {                                                                            \
    bf16x8 af[4], bw[6];                                                       \
    _Pragma("unroll") for (int mt = 0; mt < 4; ++mt) {                         \
      const int row = wr * 64 + mt * 16 + ln;                                  \
      af[mt] = *(const bf16x8*)&Asm[BUF][Q][row * 32 +                         \
                                            ((quad ^ ((row >> 1) & 3)) << 3)]; \
    }                                                                          \
    _Pragma("unroll") for (int nt = 0; nt < 6; ++nt) {                         \
      const int row = wc * 96 + nt * 16 + ln;                                  \
      bw[nt] = *(const bf16x8*)&Bsm[BUF][Q][row * 32 +                         \
                                            ((quad ^ ((row >> 1) & 3)) << 3)]; \
    }                                                                          \
    if (DOSTAGE) QKV_STAGE(T2, Q2);                                            \
    __builtin_amdgcn_s_setprio(1);                                             \
    _Pragma("unroll") for (int mt = 0; mt < 4; ++mt)                           \
      _Pragma("unroll") for (int nt = 0; nt < 6; ++nt)                         \
        acc[mt][nt] = __builtin_amdgcn_mfma_f32_16x16x32_bf16(                 \
            af[mt], bw[nt], acc[mt][nt], 0, 0, 0);                             \
    __builtin_amdgcn_s_setprio(0);                                             \
  }

__global__ __launch_bounds__(512, 2) void gemm_qkv8(
    const unsigned short* __restrict__ A, const unsigned short* __restrict__ W,
    unsigned short* __restrict__ Qb, unsigned short* __restrict__ Kb,
    unsigned short* __restrict__ Vt) {
  constexpr int K = 2048;
  __shared__ unsigned short Asm[2][2][128 * 32];   // [buf][khalf][row*32+swz]
  __shared__ unsigned short Bsm[2][2][384 * 32];

  const int t = threadIdx.x;
  const int wave = t >> 6, lane = t & 63;
  const int ln = lane & 15, quad = lane >> 4;
  const int wr = wave >> 2, wc = wave & 3;

  const int bid = blockIdx.x;
  const int wg = (bid & 7) * 64 + (bid >> 3);  // XCD swizzle, bijective
  const int n0 = (wg & 15) * 384;
  const int m0 = (wg >> 4) * 128;

  // staging: thread t covers chunk idx (l*512 + t) of each region;
  // row = l*128 + (t>>2), slot pc = t&3 holds logical chunk pc^((row>>1)&3)
  // -> pre-swizzled global source column (both-sides-or-neither, rule 21).
  const int srow = t >> 2;
  const int scol = ((t & 3) ^ ((t >> 3) & 3)) << 3;
  const unsigned short* gA = A + (size_t)(m0 + srow) * K + scol;
  const unsigned short* gW = W + (size_t)(n0 + srow) * K + scol;

  f32x4 acc[4][6] = {};

  // prologue: halves 0,1,2 in flight; wait half 0 (8 = 2 halves outstanding)
  QKV_STAGE(0, 0);
  QKV_STAGE(0, 1);
  QKV_STAGE(1, 0);
  QKV_SYNC("8");

  // main loop: tiles 0..29, 2 tiles (4 phases) per iteration, buf static
  for (int tt = 0; tt < 30; tt += 2) {
    QKV_PHASE(0, 0, true, tt + 1, 1) QKV_SYNC("8");
    QKV_PHASE(0, 1, true, tt + 2, 0) QKV_SYNC("8");
    QKV_PHASE(1, 0, true, tt + 2, 1) QKV_SYNC("8");
    QKV_PHASE(1, 1, true, tt + 3, 0) QKV_SYNC("8");
  }
  // tail: tile 30 (buf 0), tile 31 (buf 1); drain 8 -> 4 -> 0
  QKV_PHASE(0, 0, true, 31, 1) QKV_SYNC("8");
  QKV_PHASE(0, 1, false, 0, 0) QKV_SYNC("4");
  QKV_PHASE(1, 0, false, 0, 0) QKV_SYNC("0");
  QKV_PHASE(1, 1, false, 0, 0)

  // routing epilogue; 384-wide tiles straddle Q/K/V boundaries -> per-16-col
  // group dst select (wave-uniform branch per (wc,nt) group).
  const int cm0 = m0 + wr * 64 + quad * 4;
  const int cn0 = n0 + wc * 96 + ln;
#pragma unroll
  for (int mt = 0; mt < 4; ++mt)
#pragma unroll
    for (int r = 0; r < 4; ++r) {
      const int m = cm0 + mt * 16 + r;
      const int bb = m >> 11, s = m & 2047;
#pragma unroll
      for (int nt = 0; nt < 6; ++nt) {
        const int n = cn0 + nt * 16;
        const unsigned short v = f2bf(acc[mt][nt][r]);
        if (n < 2048)
          Qb[(size_t)m * 2048 + n] = v;
        else if (n < 4096)
          Kb[(size_t)m * 2048 + (n - 2048)] = v;
        else
          Vt[((size_t)(bb * 2048 + (n - 4096))) * (size_t)kS + s] = v;
      }
    }
}

#undef QKV_PHASE
#undef QKV_SYNC
#undef QKV_STAGE

// ---------------- generic C[M,N] = A[M,K] @ W[N,K]^T ----------------
// 128x128 tile, BK=64, single-buffer (R4 structure). LDS rows of 64 elems
// (8 x 16B chunks); chunk swizzle ^(row&7): conflict-free ds_read_b128 +
// coalesced staging.
template <bool OUT_BF16>
__global__ __launch_bounds__(256, 2) void gemm_bt(
    const unsigned short* __restrict__ A, const unsigned short* __restrict__ W,
    void* __restrict__ C, int M, int N, int K) {
  __shared__ unsigned short Asm[128 * 64];
  __shared__ unsigned short Bsm[128 * 64];
  const int t = threadIdx.x;
  const int wave = t >> 6, lane = t & 63;
  const int ln = lane & 15, quad = lane >> 4;
  const int wr = wave >> 1, wc = wave & 1;
  const int m0 = blockIdx.y * 128, n0 = blockIdx.x * 128;

  const int srow = t >> 3;
  const int scol = ((t & 7) ^ (srow & 7)) << 3;
  const unsigned short* gA = A + (size_t)(m0 + srow) * K + scol;
  const unsigned short* gW = W + (size_t)(n0 + srow) * K + scol;
  const size_t g32 = (size_t)32 * K;
  unsigned short* lA = Asm + wave * 512;
  unsigned short* lB = Bsm + wave * 512;

  f32x4 acc[4][4] = {};

  for (int k0 = 0; k0 < K; k0 += 64) {
    __syncthreads();
#pragma unroll
    for (int i = 0; i < 4; ++i) {
      gld_lds16(gA + i * g32, lA + i * 2048);
      gld_lds16(gW + i * g32, lB + i * 2048);
    }
    gA += 64; gW += 64;
    __syncthreads();

#pragma unroll
    for (int kk = 0; kk < 2; ++kk) {
      bf16x8 af[4], bw[4];
#pragma unroll
      for (int mt = 0; mt < 4; ++mt) {
        const int row = wr * 64 + mt * 16 + ln;
        af[mt] = *(const bf16x8*)(Asm + row * 64 +
                                  (((kk * 4 + quad) ^ (row & 7)) << 3));
      }
#pragma unroll
      for (int nt = 0; nt < 4; ++nt) {
        const int row = wc * 64 + nt * 16 + ln;
        bw[nt] = *(const bf16x8*)(Bsm + row * 64 +
                                  (((kk * 4 + quad) ^ (row & 7)) << 3));
      }
#pragma unroll
      for (int mt = 0; mt < 4; ++mt)
#pragma unroll
        for (int nt = 0; nt < 4; ++nt)
          acc[mt][nt] = __builtin_amdgcn_mfma_f32_16x16x32_bf16(
              af[mt], bw[nt], acc[mt][nt], 0, 0, 0);
    }
  }

  const int cm = m0 + wr * 64 + quad * 4;
  const int cn = n0 + wc * 64 + ln;
#pragma unroll
  for (int mt = 0; mt < 4; ++mt)
#pragma unroll
    for (int r = 0; r < 4; ++r) {
      const size_t rowoff = (size_t)(cm + mt * 16 + r) * N + cn;
      if (OUT_BF16) {
        unsigned short* Cb = (unsigned short*)C;
#pragma unroll
        for (int nt = 0; nt < 4; ++nt) Cb[rowoff + nt * 16] = f2bf(acc[mt][nt][r]);
      } else {
        float* Cf = (float*)C;
#pragma unroll
        for (int nt = 0; nt < 4; ++nt) Cf[rowoff + nt * 16] = acc[mt][nt][r];
      }
    }
}

// ---------------- causal flash attention (S^T layout) ----------------
// 128 q rows/block: 4 waves x 2 subtiles of 16. QK^T computed as
// S^T = K·Q^T (swapped MFMA operands; frag reads unchanged) so each lane's
// C-regs hold 4 kv-consecutive probs for ONE q-row (q=ln): P written as
// packed ds_write_b64 (4/subtile vs 16 scalar b16), read back as contiguous
// b128 A-frags. Single-buffered KV (48KB LDS -> 3 blocks/CU). No-max exp2
// softmax (scale*log2e folded into wq); per-lane row sums, reduced at end.
__global__ __launch_bounds__(256, 3) void flash_attn(
    const unsigned short* __restrict__ Q, const unsigned short* __restrict__ Kb,
    const unsigned short* __restrict__ Vt, unsigned short* __restrict__ Ob) {
  __shared__ unsigned short Ksm[64 * 128];
  __shared__ unsigned short Vsm[128 * 64];
  __shared__ unsigned short Psm[4][2048];  // per wave: 32 q x 64 kv
  const int t = threadIdx.x;
  const int wave = t >> 6, lane = t & 63;
  const int ln = lane & 15, quad = lane >> 4;
  const int bx = blockIdx.x;
  const int gq = bx >> 5;
  const int qt = (gq < 8) ? (15 - gq) : (gq - 8);  // heavy/light pairing
  const int bh = bx & 31, b = bh >> 4, h = bh & 15;
  const int q0 = qt * 128;

  bf16x8 qf[2][4];
#pragma unroll
  for (int st = 0; st < 2; ++st) {
    const size_t qoff =
        ((size_t)(b * kS + q0 + st * 64 + wave * 16 + ln)) * kD + h * kHD;
#pragma unroll
    for (int ks = 0; ks < 4; ++ks)
      qf[st][ks] = *(const bf16x8*)(Q + qoff + ks * 32 + quad * 8);
  }

  float lsum[2] = {0.0f, 0.0f};  // per-lane partial row-sum for q = ln
  f32x4 oa[2][8] = {};

  const int krow = t >> 4;
  const unsigned short* gK =
      Kb + ((size_t)(b * kS) + krow) * kD + h * kHD + (((t & 15) ^ krow) << 3);
  const int vrow = t >> 3;
  const unsigned short* gV =
      Vt + ((size_t)(bh * 128 + vrow)) * kS + (((t & 7) ^ (vrow & 7)) << 3);

  const int nIter = 2 * qt + 2;

  for (int it = 0; it < nIter; ++it) {
    const int kv0 = it << 6;
    __syncthreads();  // prev-iter LDS reads done
#pragma unroll
    for (int i = 0; i < 4; ++i)
      gld_lds16(gK + ((size_t)kv0 + i * 16) * kD, Ksm + i * 2048 + wave * 512);
#pragma unroll
    for (int i = 0; i < 4; ++i)
      gld_lds16(gV + (size_t)i * 32 * kS + kv0, Vsm + i * 2048 + wave * 512);
    __syncthreads();  // staging complete

    // S^T[kv][q]: A = K-frag, B = Q-frag (swapped order)
    f32x4 sc[2][4] = {};
#pragma unroll
    for (int ct = 0; ct < 4; ++ct) {
      const int row = ct * 16 + ln;
#pragma unroll
      for (int ks = 0; ks < 4; ++ks) {
        bf16x8 kf =
            *(const bf16x8*)(Ksm + row * 128 + (((ks * 4 + quad) ^ ln) << 3));
#pragma unroll
        for (int st = 0; st < 2; ++st)
          sc[st][ct] = __builtin_amdgcn_mfma_f32_16x16x32_bf16(
              kf, qf[st][ks], sc[st][ct], 0, 0, 0);
      }
    }

    // lane holds S^T[kv = ct*16+quad*4+r][q = ln]; mask, exp2, pack, b64 write
#pragma unroll
    for (int st = 0; st < 2; ++st) {
      const int q_lo = q0 + st * 64 + wave * 16;
      const bool full = (kv0 + 63 <= q_lo);  // wave-uniform
      const int qs = q_lo + ln;
      float ls = 0.0f;
#pragma unroll
      for (int ct = 0; ct < 4; ++ct) {
        const int kvb = kv0 + ct * 16 + quad * 4;
        float p[4];
#pragma unroll
        for (int r = 0; r < 4; ++r) {
          float s = sc[st][ct][r];
          if (!full && (kvb + r > qs)) s = -1e30f;
          p[r] = exp2f(s);
          ls += p[r];
        }
        const uint32_t u0 = (uint32_t)f2bf(p[0]) | ((uint32_t)f2bf(p[1]) << 16);
        const uint32_t u1 = (uint32_t)f2bf(p[2]) | ((uint32_t)f2bf(p[3]) << 16);
        const int cs = (ct * 4 + quad) ^ (ln & 14);  // 4-elem chunk swizzle
        uint2 u; u.x = u0; u.y = u1;
        *(uint2*)(&Psm[wave][(st * 16 + ln) * 64 + cs * 4]) = u;
      }
      lsum[st] += ls;
    }

    // PV: pf = P A-frag (kv-contiguous b128), vf as before; each feeds 2 MFMAs
    bf16x8 pf[2][2];
#pragma unroll
    for (int st = 0; st < 2; ++st)
#pragma unroll
      for (int ks = 0; ks < 2; ++ks)
        pf[st][ks] = *(const bf16x8*)(
            &Psm[wave][(st * 16 + ln) * 64 +
                       (((ks * 8 + quad * 2) ^ (ln & 14)) << 2)]);
#pragma unroll
    for (int ct = 0; ct < 8; ++ct) {
      const int row = ct * 16 + ln;
#pragma unroll
      for (int ks = 0; ks < 2; ++ks) {
        bf16x8 vf =
            *(const bf16x8*)(Vsm + row * 64 + (((ks * 4 + quad) ^ (ln & 7)) << 3));
#pragma unroll
        for (int st = 0; st < 2; ++st)
          oa[st][ct] = __builtin_amdgcn_mfma_f32_16x16x32_bf16(
              pf[st][ks], vf, oa[st][ct], 0, 0, 0);
      }
    }
  }

  // reduce row sums (lane ln holds partial for q=ln over its quad/reg subset)
#pragma unroll
  for (int st = 0; st < 2; ++st) {
    float l = lsum[st];
    l += __shfl_xor(l, 16, 64);
    l += __shfl_xor(l, 32, 64);  // now every lane has total for q = its ln
    float inv[4];
#pragma unroll
    for (int r = 0; r < 4; ++r)
      inv[r] = 1.0f / __shfl(l, (lane & 48) | (quad * 4 + r), 64);
#pragma unroll
    for (int r = 0; r < 4; ++r) {
      const size_t orow =
          ((size_t)(b * kS + q0 + st * 64 + wave * 16 + quad * 4 + r)) * kD +
          h * kHD + ln;
#pragma unroll
      for (int ct = 0; ct < 8; ++ct) Ob[orow + ct * 16] = f2bf(oa[st][ct][r] * inv[r]);
    }
  }
}

}  // namespace

extern "C" void kernel_launch(void* const* d_in, const int* in_sizes, int n_in,
                              void* d_out, int out_size, void* d_ws, size_t ws_size,
                              hipStream_t stream) {
  (void)in_sizes; (void)n_in; (void)out_size; (void)ws_size;
  const float* x  = (const float*)d_in[0];
  const float* wq = (const float*)d_in[3];
  const float* wk = (const float*)d_in[4];
  const float* wv = (const float*)d_in[5];
  const float* wo = (const float*)d_in[6];
  float* out = (float*)d_out;

  unsigned short* ws   = (unsigned short*)d_ws;
  unsigned short* xb   = ws;
  unsigned short* wqkv = xb + (size_t)kM * kD;   // wq,wk,wv,wo contiguous
  unsigned short* wob  = wqkv + 3 * (size_t)kD * kD;
  unsigned short* Qb   = wob + (size_t)kD * kD;
  unsigned short* Kbuf = Qb  + (size_t)kM * kD;
  unsigned short* Vt   = Kbuf + (size_t)kM * kD;  // [b*2048+d][2048]
  unsigned short* Ab   = Vt + (size_t)kM * kD;

  const int n4 = kD * kD / 4;
  cvt_all<<<dim3(n4 / 256, 6), 256, 0, stream>>>(x, wq, wk, wv, wo, xb, wqkv);

  gemm_qkv8<<<dim3(512), 512, 0, stream>>>(xb, wqkv, Qb, Kbuf, Vt);

  flash_attn<<<dim3(512), 256, 0, stream>>>(Qb, Kbuf, Vt, Ab);

  gemm_bt<false><<<dim3(kD / 128, kM / 128), 256, 0, stream>>>(Ab, wob, out, kM, kD, kD);
}

// Round 3
// 392.396 us; speedup vs baseline: 1.0749x; 1.0749x over previous
//
#include <hip/hip_runtime.h>
#include <hip/hip_bf16.h>
#include <stdint.h>

// Attention layer, MI355X. RoPE is a no-op, mask is exactly causal.
// cvt fp32->bf16 (scale*log2e folded into wq); fused QKV GEMM (V written
// transposed) as a 256x128 counted-vmcnt 4-region pipeline (16 MFMA : 8
// ds_read : 3 gld_lds per phase, vmcnt(6), stage lead 3, no XCD swizzle --
// linear dispatch with 48 n-cols gives each XCD 6 n-columns like the proven
// R4 kernel); causal flash attention (S^T trick, no-max exp2 softmax);
// out-proj GEMM at the R4 128x128 single-buffer structure.
// (R2 resubmit: container-level infra failure, kernel never measured.)

namespace {

constexpr int kB = 2;
constexpr int kS = 2048;
constexpr int kD = 2048;
constexpr int kH = 16;
constexpr int kHD = 128;
constexpr int kM = kB * kS;  // 4096 token rows

typedef __attribute__((ext_vector_type(8))) __bf16 bf16x8;
typedef __attribute__((ext_vector_type(4))) float f32x4;

__device__ __forceinline__ unsigned short f2bf(float x) {
  uint32_t u = __float_as_uint(x);
  u += 0x7fffu + ((u >> 16) & 1u);
  return (unsigned short)(u >> 16);
}

__device__ __forceinline__ void gld_lds16(const void* g, void* l) {
  __builtin_amdgcn_global_load_lds((__attribute__((address_space(1))) void*)g,
                                   (__attribute__((address_space(3))) void*)l,
                                   16, 0, 0);
}

// ---------------- all fp32 -> bf16 casts, one dispatch ----------------
__global__ void cvt_all(const float* __restrict__ x, const float* __restrict__ wq,
                        const float* __restrict__ wk, const float* __restrict__ wv,
                        const float* __restrict__ wo, unsigned short* __restrict__ xb,
                        unsigned short* __restrict__ wqkv) {
  constexpr int n4 = kD * kD / 4;
  const int i = blockIdx.x * blockDim.x + threadIdx.x;
  const int y = blockIdx.y;
  const float* src;
  unsigned short* dst;
  float s = 1.0f;
  if (y < 2) {
    src = x + (size_t)y * n4 * 4;
    dst = xb + (size_t)y * n4 * 4;
  } else {
    src = (y == 2) ? wq : (y == 3) ? wk : (y == 4) ? wv : wo;
    dst = wqkv + (size_t)(y - 2) * n4 * 4;
    if (y == 2) s = 0.08838834764831845f * 1.44269504088896340736f;
  }
  float4 v = ((const float4*)src)[i];
  ushort4 o;
  o.x = f2bf(v.x * s); o.y = f2bf(v.y * s); o.z = f2bf(v.z * s); o.w = f2bf(v.w * s);
  ((ushort4*)dst)[i] = o;
}

// ---------------- QKV GEMM: 256x128 tile, counted-vmcnt pipeline ----------
// 8 waves (4M x 2N), per-wave 64x64 (4x4 frags) -> 16 MFMA per phase.
// Phase p consumes K-half unit p (tile p>>1, khalf p&1) living in LDS region
// p%4 (A 256x32 = 16KB + B 128x32 = 8KB = 24KB; 4 regions = 96KB).
// Phase p stages unit p+3 into region (p+3)%4 (3 loads: A x2, B x1).
// Region (p+3)%4 was last read at phase p-1, whose ds_reads retire before
// its MFMA lgkm-waits, which precede barrier2(p-1) < stage issue -> safe.
// vmcnt(6) per phase = 2 stages (6 loads) allowed in flight; never drained
// in the main loop (T4). Tail drains 6->3->0. setprio around MFMA (T5).
// Grid dim3(48,16) linear dispatch: 48 % 8 == 0 -> each XCD sees only 6
// n-columns (old kernel's proven L2-friendly partition); 768 blocks = 3
// balanced generations at 1 block/CU.
#define QKV_STAGE(U)                                                           \
  {                                                                            \
    const int u_ = (U);                                                        \
    const int kof_ = (u_ >> 1) * 64 + (u_ & 1) * 32;                           \
    unsigned short* const lr_ = &Lds[u_ & 3][0];                               \
    gld_lds16(gA + kof_, lr_ + wave * 512);                                    \
    gld_lds16(gA + kof_ + (size_t)128 * 2048, lr_ + 4096 + wave * 512);        \
    gld_lds16(gW + kof_, lr_ + 8192 + wave * 512);                             \
  }

#define QKV_SYNC(VMS)                                                          \
  asm volatile("s_waitcnt vmcnt(" VMS ")" ::: "memory");                       \
  __builtin_amdgcn_s_barrier();                                                \
  asm volatile("" ::: "memory");

#define QKV_PHASE(P, DOSTAGE, VMS)                                             \
  {                                                                            \
    const int p_ = (P);                                                        \
    const unsigned short* const Ar = &Lds[p_ & 3][0];                          \
    const unsigned short* const Br = Ar + 8192;                                \
    bf16x8 af[4], bw[4];                                                       \
    _Pragma("unroll") for (int mt = 0; mt < 4; ++mt) {                         \
      const int row = wr * 64 + mt * 16 + ln;                                  \
      af[mt] = *(const bf16x8*)(Ar + row * 32 +                                \
                                ((quad ^ ((row >> 1) & 3)) << 3));             \
    }                                                                          \
    _Pragma("unroll") for (int nt = 0; nt < 4; ++nt) {                         \
      const int row = wc * 64 + nt * 16 + ln;                                  \
      bw[nt] = *(const bf16x8*)(Br + row * 32 +                                \
                                ((quad ^ ((row >> 1) & 3)) << 3));             \
    }                                                                          \
    if (DOSTAGE) QKV_STAGE(p_ + 3);                                            \
    __builtin_amdgcn_s_barrier();                                              \
    __builtin_amdgcn_s_setprio(1);                                             \
    _Pragma("unroll") for (int mt = 0; mt < 4; ++mt)                           \
      _Pragma("unroll") for (int nt = 0; nt < 4; ++nt)                         \
        acc[mt][nt] = __builtin_amdgcn_mfma_f32_16x16x32_bf16(                 \
            af[mt], bw[nt], acc[mt][nt], 0, 0, 0);                             \
    __builtin_amdgcn_s_setprio(0);                                             \
    QKV_SYNC(VMS)                                                              \
  }

__global__ __launch_bounds__(512, 2) void gemm_qkv8b(
    const unsigned short* __restrict__ A, const unsigned short* __restrict__ W,
    unsigned short* __restrict__ Qb, unsigned short* __restrict__ Kb,
    unsigned short* __restrict__ Vt) {
  constexpr int K = 2048;
  __shared__ unsigned short Lds[4][12288];  // region: A[256x32] then B[128x32]

  const int t = threadIdx.x;
  const int wave = t >> 6, lane = t & 63;
  const int ln = lane & 15, quad = lane >> 4;
  const int wr = wave >> 1, wc = wave & 1;

  const int n0 = blockIdx.x * 128;  // 48 n-tiles, x fastest -> 6 n-cols/XCD
  const int m0 = blockIdx.y * 256;

  // staging: thread t covers row t>>2 (4 threads/row, 64B/row), slot t&3
  // holds logical chunk (t&3)^((row>>1)&3) -> pre-swizzled global column
  // (both-sides-or-neither, rule 21). (row>>1)&3 == (t>>3)&3, and adding
  // 128 to the row (A's second load) doesn't change it (128 % 8 == 0).
  const int srow = t >> 2;
  const int scol = ((t & 3) ^ ((t >> 3) & 3)) << 3;
  const unsigned short* gA = A + (size_t)(m0 + srow) * K + scol;
  const unsigned short* gW = W + (size_t)(n0 + srow) * K + scol;

  f32x4 acc[4][4] = {};

  // prologue: units 0,1,2 in flight (9 loads); wait unit 0 (keep 6)
  QKV_STAGE(0);
  QKV_STAGE(1);
  QKV_STAGE(2);
  QKV_SYNC("6");

  // phases 0..60: stage unit p+3, keep 2 stages in flight
  for (int p = 0; p < 61; ++p) QKV_PHASE(p, true, "6");
  // tail: drain 6 -> 3 -> 0
  QKV_PHASE(61, false, "3");
  QKV_PHASE(62, false, "0");
  // final phase: no stage, no sync
  {
    const unsigned short* const Ar = &Lds[3][0];
    const unsigned short* const Br = Ar + 8192;
    bf16x8 af[4], bw[4];
#pragma unroll
    for (int mt = 0; mt < 4; ++mt) {
      const int row = wr * 64 + mt * 16 + ln;
      af[mt] = *(const bf16x8*)(Ar + row * 32 + ((quad ^ ((row >> 1) & 3)) << 3));
    }
#pragma unroll
    for (int nt = 0; nt < 4; ++nt) {
      const int row = wc * 64 + nt * 16 + ln;
      bw[nt] = *(const bf16x8*)(Br + row * 32 + ((quad ^ ((row >> 1) & 3)) << 3));
    }
#pragma unroll
    for (int mt = 0; mt < 4; ++mt)
#pragma unroll
      for (int nt = 0; nt < 4; ++nt)
        acc[mt][nt] = __builtin_amdgcn_mfma_f32_16x16x32_bf16(
            af[mt], bw[nt], acc[mt][nt], 0, 0, 0);
  }

  // routing epilogue; 128-wide n-tiles never straddle Q/K/V boundaries.
  const int cm0 = m0 + wr * 64 + quad * 4;
  const int cn0 = n0 + wc * 64 + ln;
  if (n0 < 4096) {
    unsigned short* dst = (n0 < 2048) ? Qb : Kb;
    const int nbase = cn0 & 2047;
#pragma unroll
    for (int mt = 0; mt < 4; ++mt)
#pragma unroll
      for (int r = 0; r < 4; ++r) {
        const size_t rowoff = (size_t)(cm0 + mt * 16 + r) * kD + nbase;
#pragma unroll
        for (int nt = 0; nt < 4; ++nt) dst[rowoff + nt * 16] = f2bf(acc[mt][nt][r]);
      }
  } else {
#pragma unroll
    for (int mt = 0; mt < 4; ++mt)
#pragma unroll
      for (int r = 0; r < 4; ++r) {
        const int m = cm0 + mt * 16 + r;
        const int bb = m >> 11, s = m & 2047;
#pragma unroll
        for (int nt = 0; nt < 4; ++nt) {
          const int d = cn0 + nt * 16 - 4096;
          Vt[((size_t)(bb * 2048 + d)) * (size_t)kS + s] = f2bf(acc[mt][nt][r]);
        }
      }
  }
}

#undef QKV_PHASE
#undef QKV_SYNC
#undef QKV_STAGE

// ---------------- generic C[M,N] = A[M,K] @ W[N,K]^T ----------------
// 128x128 tile, BK=64, single-buffer (R4 structure). LDS rows of 64 elems
// (8 x 16B chunks); chunk swizzle ^(row&7): conflict-free ds_read_b128 +
// coalesced staging.
template <bool OUT_BF16>
__global__ __launch_bounds__(256, 2) void gemm_bt(
    const unsigned short* __restrict__ A, const unsigned short* __restrict__ W,
    void* __restrict__ C, int M, int N, int K) {
  __shared__ unsigned short Asm[128 * 64];
  __shared__ unsigned short Bsm[128 * 64];
  const int t = threadIdx.x;
  const int wave = t >> 6, lane = t & 63;
  const int ln = lane & 15, quad = lane >> 4;
  const int wr = wave >> 1, wc = wave & 1;
  const int m0 = blockIdx.y * 128, n0 = blockIdx.x * 128;

  const int srow = t >> 3;
  const int scol = ((t & 7) ^ (srow & 7)) << 3;
  const unsigned short* gA = A + (size_t)(m0 + srow) * K + scol;
  const unsigned short* gW = W + (size_t)(n0 + srow) * K + scol;
  const size_t g32 = (size_t)32 * K;
  unsigned short* lA = Asm + wave * 512;
  unsigned short* lB = Bsm + wave * 512;

  f32x4 acc[4][4] = {};

  for (int k0 = 0; k0 < K; k0 += 64) {
    __syncthreads();
#pragma unroll
    for (int i = 0; i < 4; ++i) {
      gld_lds16(gA + i * g32, lA + i * 2048);
      gld_lds16(gW + i * g32, lB + i * 2048);
    }
    gA += 64; gW += 64;
    __syncthreads();

#pragma unroll
    for (int kk = 0; kk < 2; ++kk) {
      bf16x8 af[4], bw[4];
#pragma unroll
      for (int mt = 0; mt < 4; ++mt) {
        const int row = wr * 64 + mt * 16 + ln;
        af[mt] = *(const bf16x8*)(Asm + row * 64 +
                                  (((kk * 4 + quad) ^ (row & 7)) << 3));
      }
#pragma unroll
      for (int nt = 0; nt < 4; ++nt) {
        const int row = wc * 64 + nt * 16 + ln;
        bw[nt] = *(const bf16x8*)(Bsm + row * 64 +
                                  (((kk * 4 + quad) ^ (row & 7)) << 3));
      }
#pragma unroll
      for (int mt = 0; mt < 4; ++mt)
#pragma unroll
        for (int nt = 0; nt < 4; ++nt)
          acc[mt][nt] = __builtin_amdgcn_mfma_f32_16x16x32_bf16(
              af[mt], bw[nt], acc[mt][nt], 0, 0, 0);
    }
  }

  const int cm = m0 + wr * 64 + quad * 4;
  const int cn = n0 + wc * 64 + ln;
#pragma unroll
  for (int mt = 0; mt < 4; ++mt)
#pragma unroll
    for (int r = 0; r < 4; ++r) {
      const size_t rowoff = (size_t)(cm + mt * 16 + r) * N + cn;
      if (OUT_BF16) {
        unsigned short* Cb = (unsigned short*)C;
#pragma unroll
        for (int nt = 0; nt < 4; ++nt) Cb[rowoff + nt * 16] = f2bf(acc[mt][nt][r]);
      } else {
        float* Cf = (float*)C;
#pragma unroll
        for (int nt = 0; nt < 4; ++nt) Cf[rowoff + nt * 16] = acc[mt][nt][r];
      }
    }
}

// ---------------- causal flash attention (S^T layout) ----------------
// 128 q rows/block: 4 waves x 2 subtiles of 16. QK^T computed as
// S^T = K·Q^T (swapped MFMA operands; frag reads unchanged) so each lane's
// C-regs hold 4 kv-consecutive probs for ONE q-row (q=ln): P written as
// packed ds_write_b64 (4/subtile vs 16 scalar b16), read back as contiguous
// b128 A-frags. Single-buffered KV (48KB LDS -> 3 blocks/CU). No-max exp2
// softmax (scale*log2e folded into wq); per-lane row sums, reduced at end.
__global__ __launch_bounds__(256, 3) void flash_attn(
    const unsigned short* __restrict__ Q, const unsigned short* __restrict__ Kb,
    const unsigned short* __restrict__ Vt, unsigned short* __restrict__ Ob) {
  __shared__ unsigned short Ksm[64 * 128];
  __shared__ unsigned short Vsm[128 * 64];
  __shared__ unsigned short Psm[4][2048];  // per wave: 32 q x 64 kv
  const int t = threadIdx.x;
  const int wave = t >> 6, lane = t & 63;
  const int ln = lane & 15, quad = lane >> 4;
  const int bx = blockIdx.x;
  const int gq = bx >> 5;
  const int qt = (gq < 8) ? (15 - gq) : (gq - 8);  // heavy/light pairing
  const int bh = bx & 31, b = bh >> 4, h = bh & 15;
  const int q0 = qt * 128;

  bf16x8 qf[2][4];
#pragma unroll
  for (int st = 0; st < 2; ++st) {
    const size_t qoff =
        ((size_t)(b * kS + q0 + st * 64 + wave * 16 + ln)) * kD + h * kHD;
#pragma unroll
    for (int ks = 0; ks < 4; ++ks)
      qf[st][ks] = *(const bf16x8*)(Q + qoff + ks * 32 + quad * 8);
  }

  float lsum[2] = {0.0f, 0.0f};  // per-lane partial row-sum for q = ln
  f32x4 oa[2][8] = {};

  const int krow = t >> 4;
  const unsigned short* gK =
      Kb + ((size_t)(b * kS) + krow) * kD + h * kHD + (((t & 15) ^ krow) << 3);
  const int vrow = t >> 3;
  const unsigned short* gV =
      Vt + ((size_t)(bh * 128 + vrow)) * kS + (((t & 7) ^ (vrow & 7)) << 3);

  const int nIter = 2 * qt + 2;

  for (int it = 0; it < nIter; ++it) {
    const int kv0 = it << 6;
    __syncthreads();  // prev-iter LDS reads done
#pragma unroll
    for (int i = 0; i < 4; ++i)
      gld_lds16(gK + ((size_t)kv0 + i * 16) * kD, Ksm + i * 2048 + wave * 512);
#pragma unroll
    for (int i = 0; i < 4; ++i)
      gld_lds16(gV + (size_t)i * 32 * kS + kv0, Vsm + i * 2048 + wave * 512);
    __syncthreads();  // staging complete

    // S^T[kv][q]: A = K-frag, B = Q-frag (swapped order)
    f32x4 sc[2][4] = {};
#pragma unroll
    for (int ct = 0; ct < 4; ++ct) {
      const int row = ct * 16 + ln;
#pragma unroll
      for (int ks = 0; ks < 4; ++ks) {
        bf16x8 kf =
            *(const bf16x8*)(Ksm + row * 128 + (((ks * 4 + quad) ^ ln) << 3));
#pragma unroll
        for (int st = 0; st < 2; ++st)
          sc[st][ct] = __builtin_amdgcn_mfma_f32_16x16x32_bf16(
              kf, qf[st][ks], sc[st][ct], 0, 0, 0);
      }
    }

    // lane holds S^T[kv = ct*16+quad*4+r][q = ln]; mask, exp2, pack, b64 write
#pragma unroll
    for (int st = 0; st < 2; ++st) {
      const int q_lo = q0 + st * 64 + wave * 16;
      const bool full = (kv0 + 63 <= q_lo);  // wave-uniform
      const int qs = q_lo + ln;
      float ls = 0.0f;
#pragma unroll
      for (int ct = 0; ct < 4; ++ct) {
        const int kvb = kv0 + ct * 16 + quad * 4;
        float p[4];
#pragma unroll
        for (int r = 0; r < 4; ++r) {
          float s = sc[st][ct][r];
          if (!full && (kvb + r > qs)) s = -1e30f;
          p[r] = exp2f(s);
          ls += p[r];
        }
        const uint32_t u0 = (uint32_t)f2bf(p[0]) | ((uint32_t)f2bf(p[1]) << 16);
        const uint32_t u1 = (uint32_t)f2bf(p[2]) | ((uint32_t)f2bf(p[3]) << 16);
        const int cs = (ct * 4 + quad) ^ (ln & 14);  // 4-elem chunk swizzle
        uint2 u; u.x = u0; u.y = u1;
        *(uint2*)(&Psm[wave][(st * 16 + ln) * 64 + cs * 4]) = u;
      }
      lsum[st] += ls;
    }

    // PV: pf = P A-frag (kv-contiguous b128), vf as before; each feeds 2 MFMAs
    bf16x8 pf[2][2];
#pragma unroll
    for (int st = 0; st < 2; ++st)
#pragma unroll
      for (int ks = 0; ks < 2; ++ks)
        pf[st][ks] = *(const bf16x8*)(
            &Psm[wave][(st * 16 + ln) * 64 +
                       (((ks * 8 + quad * 2) ^ (ln & 14)) << 2)]);
#pragma unroll
    for (int ct = 0; ct < 8; ++ct) {
      const int row = ct * 16 + ln;
#pragma unroll
      for (int ks = 0; ks < 2; ++ks) {
        bf16x8 vf =
            *(const bf16x8*)(Vsm + row * 64 + (((ks * 4 + quad) ^ (ln & 7)) << 3));
#pragma unroll
        for (int st = 0; st < 2; ++st)
          oa[st][ct] = __builtin_amdgcn_mfma_f32_16x16x32_bf16(
              pf[st][ks], vf, oa[st][ct], 0, 0, 0);
      }
    }
  }

  // reduce row sums (lane ln holds partial for q=ln over its quad/reg subset)
#pragma unroll
  for (int st = 0; st < 2; ++st) {
    float l = lsum[st];
    l += __shfl_xor(l, 16, 64);
    l += __shfl_xor(l, 32, 64);  // now every lane has total for q = its ln
    float inv[4];
#pragma unroll
    for (int r = 0; r < 4; ++r)
      inv[r] = 1.0f / __shfl(l, (lane & 48) | (quad * 4 + r), 64);
#pragma unroll
    for (int r = 0; r < 4; ++r) {
      const size_t orow =
          ((size_t)(b * kS + q0 + st * 64 + wave * 16 + quad * 4 + r)) * kD +
          h * kHD + ln;
#pragma unroll
      for (int ct = 0; ct < 8; ++ct) Ob[orow + ct * 16] = f2bf(oa[st][ct][r] * inv[r]);
    }
  }
}

}  // namespace

extern "C" void kernel_launch(void* const* d_in, const int* in_sizes, int n_in,
                              void* d_out, int out_size, void* d_ws, size_t ws_size,
                              hipStream_t stream) {
  (void)in_sizes; (void)n_in; (void)out_size; (void)ws_size;
  const float* x  = (const float*)d_in[0];
  const float* wq = (const float*)d_in[3];
  const float* wk = (const float*)d_in[4];
  const float* wv = (const float*)d_in[5];
  const float* wo = (const float*)d_in[6];
  float* out = (float*)d_out;

  unsigned short* ws   = (unsigned short*)d_ws;
  unsigned short* xb   = ws;
  unsigned short* wqkv = xb + (size_t)kM * kD;   // wq,wk,wv,wo contiguous
  unsigned short* wob  = wqkv + 3 * (size_t)kD * kD;
  unsigned short* Qb   = wob + (size_t)kD * kD;
  unsigned short* Kbuf = Qb  + (size_t)kM * kD;
  unsigned short* Vt   = Kbuf + (size_t)kM * kD;  // [b*2048+d][2048]
  unsigned short* Ab   = Vt + (size_t)kM * kD;

  const int n4 = kD * kD / 4;
  cvt_all<<<dim3(n4 / 256, 6), 256, 0, stream>>>(x, wq, wk, wv, wo, xb, wqkv);

  gemm_qkv8b<<<dim3(48, 16), 512, 0, stream>>>(xb, wqkv, Qb, Kbuf, Vt);

  flash_attn<<<dim3(512), 256, 0, stream>>>(Qb, Kbuf, Vt, Ab);

  gemm_bt<false><<<dim3(kD / 128, kM / 128), 256, 0, stream>>>(Ab, wob, out, kM, kD, kD);
}

// Round 4
// 387.880 us; speedup vs baseline: 1.0874x; 1.0116x over previous
//
#include <hip/hip_runtime.h>
#include <hip/hip_bf16.h>
#include <stdint.h>

// Attention layer, MI355X. RoPE is a no-op, mask is exactly causal.
// cvt fp32->bf16 (scale*log2e folded into wq); fused QKV GEMM (V written
// transposed) at the proven R4 structure (128x128 tile, BK=64, single-buffer,
// 2 blocks/CU -- inter-block TLP beats source-level pipelining here: the
// counted-vmcnt 4-region pipeline was tried twice (128x384, 256x128) and
// regressed to 149/124 us vs 103, because 96KB+ LDS forces 1 block/CU
// lockstep); causal flash attention (S^T trick, no-max exp2 softmax);
// out-proj GEMM same R4 structure. V epilogue stores packed ushort4.

namespace {

constexpr int kB = 2;
constexpr int kS = 2048;
constexpr int kD = 2048;
constexpr int kH = 16;
constexpr int kHD = 128;
constexpr int kM = kB * kS;  // 4096 token rows

typedef __attribute__((ext_vector_type(8))) __bf16 bf16x8;
typedef __attribute__((ext_vector_type(4))) float f32x4;

__device__ __forceinline__ unsigned short f2bf(float x) {
  uint32_t u = __float_as_uint(x);
  u += 0x7fffu + ((u >> 16) & 1u);
  return (unsigned short)(u >> 16);
}

__device__ __forceinline__ void gld_lds16(const void* g, void* l) {
  __builtin_amdgcn_global_load_lds((__attribute__((address_space(1))) void*)g,
                                   (__attribute__((address_space(3))) void*)l,
                                   16, 0, 0);
}

// ---------------- all fp32 -> bf16 casts, one dispatch ----------------
__global__ void cvt_all(const float* __restrict__ x, const float* __restrict__ wq,
                        const float* __restrict__ wk, const float* __restrict__ wv,
                        const float* __restrict__ wo, unsigned short* __restrict__ xb,
                        unsigned short* __restrict__ wqkv) {
  constexpr int n4 = kD * kD / 4;
  const int i = blockIdx.x * blockDim.x + threadIdx.x;
  const int y = blockIdx.y;
  const float* src;
  unsigned short* dst;
  float s = 1.0f;
  if (y < 2) {
    src = x + (size_t)y * n4 * 4;
    dst = xb + (size_t)y * n4 * 4;
  } else {
    src = (y == 2) ? wq : (y == 3) ? wk : (y == 4) ? wv : wo;
    dst = wqkv + (size_t)(y - 2) * n4 * 4;
    if (y == 2) s = 0.08838834764831845f * 1.44269504088896340736f;
  }
  float4 v = ((const float4*)src)[i];
  ushort4 o;
  o.x = f2bf(v.x * s); o.y = f2bf(v.y * s); o.z = f2bf(v.z * s); o.w = f2bf(v.w * s);
  ((ushort4*)dst)[i] = o;
}

// ---------------- fused QKV GEMM with routing epilogue ----------------
// 128x128 tile, BK=64, single-buffer, 2 blocks/CU. LDS rows of 64 elems
// (8 x 16B chunks); chunk swizzle ^(row&7): conflict-free ds_read_b128 +
// coalesced staging via pre-swizzled global source (rule 21 both-sides).
__global__ __launch_bounds__(256, 2) void gemm_qkv(
    const unsigned short* __restrict__ A, const unsigned short* __restrict__ W,
    unsigned short* __restrict__ Qb, unsigned short* __restrict__ Kb,
    unsigned short* __restrict__ Vt) {
  constexpr int K = 2048;
  __shared__ unsigned short Asm[128 * 64];
  __shared__ unsigned short Bsm[128 * 64];
  const int t = threadIdx.x;
  const int wave = t >> 6, lane = t & 63;
  const int ln = lane & 15, quad = lane >> 4;
  const int wr = wave >> 1, wc = wave & 1;
  const int m0 = blockIdx.y * 128, n0 = blockIdx.x * 128;

  const int srow = t >> 3;
  const int scol = ((t & 7) ^ (srow & 7)) << 3;
  const unsigned short* gA = A + (size_t)(m0 + srow) * K + scol;
  const unsigned short* gW = W + (size_t)(n0 + srow) * K + scol;
  const size_t g32 = (size_t)32 * K;
  unsigned short* lA = Asm + wave * 512;
  unsigned short* lB = Bsm + wave * 512;

  f32x4 acc[4][4] = {};

  for (int k0 = 0; k0 < K; k0 += 64) {
    __syncthreads();
#pragma unroll
    for (int i = 0; i < 4; ++i) {
      gld_lds16(gA + i * g32, lA + i * 2048);
      gld_lds16(gW + i * g32, lB + i * 2048);
    }
    gA += 64; gW += 64;
    __syncthreads();

#pragma unroll
    for (int kk = 0; kk < 2; ++kk) {
      bf16x8 af[4], bw[4];
#pragma unroll
      for (int mt = 0; mt < 4; ++mt) {
        const int row = wr * 64 + mt * 16 + ln;
        af[mt] = *(const bf16x8*)(Asm + row * 64 +
                                  (((kk * 4 + quad) ^ (row & 7)) << 3));
      }
#pragma unroll
      for (int nt = 0; nt < 4; ++nt) {
        const int row = wc * 64 + nt * 16 + ln;
        bw[nt] = *(const bf16x8*)(Bsm + row * 64 +
                                  (((kk * 4 + quad) ^ (row & 7)) << 3));
      }
#pragma unroll
      for (int mt = 0; mt < 4; ++mt)
#pragma unroll
        for (int nt = 0; nt < 4; ++nt)
          acc[mt][nt] = __builtin_amdgcn_mfma_f32_16x16x32_bf16(
              af[mt], bw[nt], acc[mt][nt], 0, 0, 0);
    }
  }

  const int cm = m0 + wr * 64 + quad * 4;
  const int cn = n0 + wc * 64 + ln;
  if (n0 < 4096) {
    unsigned short* dst = (n0 < 2048) ? Qb : Kb;
    const int cnl = cn & 2047;
#pragma unroll
    for (int mt = 0; mt < 4; ++mt)
#pragma unroll
      for (int r = 0; r < 4; ++r) {
        const size_t rowoff = (size_t)(cm + mt * 16 + r) * kD + cnl;
#pragma unroll
        for (int nt = 0; nt < 4; ++nt) dst[rowoff + nt * 16] = f2bf(acc[mt][nt][r]);
      }
  } else {
    // V transpose epilogue: the 4 r-values of one (mt,nt) frag are
    // s-consecutive (cm % 4 == 0, same 2048-row block) -> one ushort4 store.
#pragma unroll
    for (int mt = 0; mt < 4; ++mt) {
      const int m = cm + mt * 16;  // r = 0 base; m % 4 == 0
      const int bb = m >> 11, s = m & 2047;
#pragma unroll
      for (int nt = 0; nt < 4; ++nt) {
        const int d = cn + nt * 16 - 4096;
        ushort4 pk;
        pk.x = f2bf(acc[mt][nt][0]);
        pk.y = f2bf(acc[mt][nt][1]);
        pk.z = f2bf(acc[mt][nt][2]);
        pk.w = f2bf(acc[mt][nt][3]);
        *(ushort4*)&Vt[((size_t)(bb * 2048 + d)) * (size_t)kS + s] = pk;
      }
    }
  }
}

// ---------------- generic C[M,N] = A[M,K] @ W[N,K]^T ----------------
// 128x128 tile, BK=64, single-buffer (R4 structure). LDS rows of 64 elems
// (8 x 16B chunks); chunk swizzle ^(row&7): conflict-free ds_read_b128 +
// coalesced staging.
template <bool OUT_BF16>
__global__ __launch_bounds__(256, 2) void gemm_bt(
    const unsigned short* __restrict__ A, const unsigned short* __restrict__ W,
    void* __restrict__ C, int M, int N, int K) {
  __shared__ unsigned short Asm[128 * 64];
  __shared__ unsigned short Bsm[128 * 64];
  const int t = threadIdx.x;
  const int wave = t >> 6, lane = t & 63;
  const int ln = lane & 15, quad = lane >> 4;
  const int wr = wave >> 1, wc = wave & 1;
  const int m0 = blockIdx.y * 128, n0 = blockIdx.x * 128;

  const int srow = t >> 3;
  const int scol = ((t & 7) ^ (srow & 7)) << 3;
  const unsigned short* gA = A + (size_t)(m0 + srow) * K + scol;
  const unsigned short* gW = W + (size_t)(n0 + srow) * K + scol;
  const size_t g32 = (size_t)32 * K;
  unsigned short* lA = Asm + wave * 512;
  unsigned short* lB = Bsm + wave * 512;

  f32x4 acc[4][4] = {};

  for (int k0 = 0; k0 < K; k0 += 64) {
    __syncthreads();
#pragma unroll
    for (int i = 0; i < 4; ++i) {
      gld_lds16(gA + i * g32, lA + i * 2048);
      gld_lds16(gW + i * g32, lB + i * 2048);
    }
    gA += 64; gW += 64;
    __syncthreads();

#pragma unroll
    for (int kk = 0; kk < 2; ++kk) {
      bf16x8 af[4], bw[4];
#pragma unroll
      for (int mt = 0; mt < 4; ++mt) {
        const int row = wr * 64 + mt * 16 + ln;
        af[mt] = *(const bf16x8*)(Asm + row * 64 +
                                  (((kk * 4 + quad) ^ (row & 7)) << 3));
      }
#pragma unroll
      for (int nt = 0; nt < 4; ++nt) {
        const int row = wc * 64 + nt * 16 + ln;
        bw[nt] = *(const bf16x8*)(Bsm + row * 64 +
                                  (((kk * 4 + quad) ^ (row & 7)) << 3));
      }
#pragma unroll
      for (int mt = 0; mt < 4; ++mt)
#pragma unroll
        for (int nt = 0; nt < 4; ++nt)
          acc[mt][nt] = __builtin_amdgcn_mfma_f32_16x16x32_bf16(
              af[mt], bw[nt], acc[mt][nt], 0, 0, 0);
    }
  }

  const int cm = m0 + wr * 64 + quad * 4;
  const int cn = n0 + wc * 64 + ln;
#pragma unroll
  for (int mt = 0; mt < 4; ++mt)
#pragma unroll
    for (int r = 0; r < 4; ++r) {
      const size_t rowoff = (size_t)(cm + mt * 16 + r) * N + cn;
      if (OUT_BF16) {
        unsigned short* Cb = (unsigned short*)C;
#pragma unroll
        for (int nt = 0; nt < 4; ++nt) Cb[rowoff + nt * 16] = f2bf(acc[mt][nt][r]);
      } else {
        float* Cf = (float*)C;
#pragma unroll
        for (int nt = 0; nt < 4; ++nt) Cf[rowoff + nt * 16] = acc[mt][nt][r];
      }
    }
}

// ---------------- causal flash attention (S^T layout) ----------------
// 128 q rows/block: 4 waves x 2 subtiles of 16. QK^T computed as
// S^T = K·Q^T (swapped MFMA operands; frag reads unchanged) so each lane's
// C-regs hold 4 kv-consecutive probs for ONE q-row (q=ln): P written as
// packed ds_write_b64 (4/subtile vs 16 scalar b16), read back as contiguous
// b128 A-frags. Single-buffered KV (48KB LDS -> 3 blocks/CU). No-max exp2
// softmax (scale*log2e folded into wq); per-lane row sums, reduced at end.
__global__ __launch_bounds__(256, 3) void flash_attn(
    const unsigned short* __restrict__ Q, const unsigned short* __restrict__ Kb,
    const unsigned short* __restrict__ Vt, unsigned short* __restrict__ Ob) {
  __shared__ unsigned short Ksm[64 * 128];
  __shared__ unsigned short Vsm[128 * 64];
  __shared__ unsigned short Psm[4][2048];  // per wave: 32 q x 64 kv
  const int t = threadIdx.x;
  const int wave = t >> 6, lane = t & 63;
  const int ln = lane & 15, quad = lane >> 4;
  const int bx = blockIdx.x;
  const int gq = bx >> 5;
  const int qt = (gq < 8) ? (15 - gq) : (gq - 8);  // heavy/light pairing
  const int bh = bx & 31, b = bh >> 4, h = bh & 15;
  const int q0 = qt * 128;

  bf16x8 qf[2][4];
#pragma unroll
  for (int st = 0; st < 2; ++st) {
    const size_t qoff =
        ((size_t)(b * kS + q0 + st * 64 + wave * 16 + ln)) * kD + h * kHD;
#pragma unroll
    for (int ks = 0; ks < 4; ++ks)
      qf[st][ks] = *(const bf16x8*)(Q + qoff + ks * 32 + quad * 8);
  }

  float lsum[2] = {0.0f, 0.0f};  // per-lane partial row-sum for q = ln
  f32x4 oa[2][8] = {};

  const int krow = t >> 4;
  const unsigned short* gK =
      Kb + ((size_t)(b * kS) + krow) * kD + h * kHD + (((t & 15) ^ krow) << 3);
  const int vrow = t >> 3;
  const unsigned short* gV =
      Vt + ((size_t)(bh * 128 + vrow)) * kS + (((t & 7) ^ (vrow & 7)) << 3);

  const int nIter = 2 * qt + 2;

  for (int it = 0; it < nIter; ++it) {
    const int kv0 = it << 6;
    __syncthreads();  // prev-iter LDS reads done
#pragma unroll
    for (int i = 0; i < 4; ++i)
      gld_lds16(gK + ((size_t)kv0 + i * 16) * kD, Ksm + i * 2048 + wave * 512);
#pragma unroll
    for (int i = 0; i < 4; ++i)
      gld_lds16(gV + (size_t)i * 32 * kS + kv0, Vsm + i * 2048 + wave * 512);
    __syncthreads();  // staging complete

    // S^T[kv][q]: A = K-frag, B = Q-frag (swapped order)
    f32x4 sc[2][4] = {};
#pragma unroll
    for (int ct = 0; ct < 4; ++ct) {
      const int row = ct * 16 + ln;
#pragma unroll
      for (int ks = 0; ks < 4; ++ks) {
        bf16x8 kf =
            *(const bf16x8*)(Ksm + row * 128 + (((ks * 4 + quad) ^ ln) << 3));
#pragma unroll
        for (int st = 0; st < 2; ++st)
          sc[st][ct] = __builtin_amdgcn_mfma_f32_16x16x32_bf16(
              kf, qf[st][ks], sc[st][ct], 0, 0, 0);
      }
    }

    // lane holds S^T[kv = ct*16+quad*4+r][q = ln]; mask, exp2, pack, b64 write
#pragma unroll
    for (int st = 0; st < 2; ++st) {
      const int q_lo = q0 + st * 64 + wave * 16;
      const bool full = (kv0 + 63 <= q_lo);  // wave-uniform
      const int qs = q_lo + ln;
      float ls = 0.0f;
#pragma unroll
      for (int ct = 0; ct < 4; ++ct) {
        const int kvb = kv0 + ct * 16 + quad * 4;
        float p[4];
#pragma unroll
        for (int r = 0; r < 4; ++r) {
          float s = sc[st][ct][r];
          if (!full && (kvb + r > qs)) s = -1e30f;
          p[r] = exp2f(s);
          ls += p[r];
        }
        const uint32_t u0 = (uint32_t)f2bf(p[0]) | ((uint32_t)f2bf(p[1]) << 16);
        const uint32_t u1 = (uint32_t)f2bf(p[2]) | ((uint32_t)f2bf(p[3]) << 16);
        const int cs = (ct * 4 + quad) ^ (ln & 14);  // 4-elem chunk swizzle
        uint2 u; u.x = u0; u.y = u1;
        *(uint2*)(&Psm[wave][(st * 16 + ln) * 64 + cs * 4]) = u;
      }
      lsum[st] += ls;
    }

    // PV: pf = P A-frag (kv-contiguous b128), vf as before; each feeds 2 MFMAs
    bf16x8 pf[2][2];
#pragma unroll
    for (int st = 0; st < 2; ++st)
#pragma unroll
      for (int ks = 0; ks < 2; ++ks)
        pf[st][ks] = *(const bf16x8*)(
            &Psm[wave][(st * 16 + ln) * 64 +
                       (((ks * 8 + quad * 2) ^ (ln & 14)) << 2)]);
#pragma unroll
    for (int ct = 0; ct < 8; ++ct) {
      const int row = ct * 16 + ln;
#pragma unroll
      for (int ks = 0; ks < 2; ++ks) {
        bf16x8 vf =
            *(const bf16x8*)(Vsm + row * 64 + (((ks * 4 + quad) ^ (ln & 7)) << 3));
#pragma unroll
        for (int st = 0; st < 2; ++st)
          oa[st][ct] = __builtin_amdgcn_mfma_f32_16x16x32_bf16(
              pf[st][ks], vf, oa[st][ct], 0, 0, 0);
      }
    }
  }

  // reduce row sums (lane ln holds partial for q=ln over its quad/reg subset)
#pragma unroll
  for (int st = 0; st < 2; ++st) {
    float l = lsum[st];
    l += __shfl_xor(l, 16, 64);
    l += __shfl_xor(l, 32, 64);  // now every lane has total for q = its ln
    float inv[4];
#pragma unroll
    for (int r = 0; r < 4; ++r)
      inv[r] = 1.0f / __shfl(l, (lane & 48) | (quad * 4 + r), 64);
#pragma unroll
    for (int r = 0; r < 4; ++r) {
      const size_t orow =
          ((size_t)(b * kS + q0 + st * 64 + wave * 16 + quad * 4 + r)) * kD +
          h * kHD + ln;
#pragma unroll
      for (int ct = 0; ct < 8; ++ct) Ob[orow + ct * 16] = f2bf(oa[st][ct][r] * inv[r]);
    }
  }
}

}  // namespace

extern "C" void kernel_launch(void* const* d_in, const int* in_sizes, int n_in,
                              void* d_out, int out_size, void* d_ws, size_t ws_size,
                              hipStream_t stream) {
  (void)in_sizes; (void)n_in; (void)out_size; (void)ws_size;
  const float* x  = (const float*)d_in[0];
  const float* wq = (const float*)d_in[3];
  const float* wk = (const float*)d_in[4];
  const float* wv = (const float*)d_in[5];
  const float* wo = (const float*)d_in[6];
  float* out = (float*)d_out;

  unsigned short* ws   = (unsigned short*)d_ws;
  unsigned short* xb   = ws;
  unsigned short* wqkv = xb + (size_t)kM * kD;   // wq,wk,wv,wo contiguous
  unsigned short* wob  = wqkv + 3 * (size_t)kD * kD;
  unsigned short* Qb   = wob + (size_t)kD * kD;
  unsigned short* Kbuf = Qb  + (size_t)kM * kD;
  unsigned short* Vt   = Kbuf + (size_t)kM * kD;  // [b*2048+d][2048]
  unsigned short* Ab   = Vt + (size_t)kM * kD;

  const int n4 = kD * kD / 4;
  cvt_all<<<dim3(n4 / 256, 6), 256, 0, stream>>>(x, wq, wk, wv, wo, xb, wqkv);

  gemm_qkv<<<dim3(6144 / 128, kM / 128), 256, 0, stream>>>(xb, wqkv, Qb, Kbuf, Vt);

  flash_attn<<<dim3(512), 256, 0, stream>>>(Qb, Kbuf, Vt, Ab);

  gemm_bt<false><<<dim3(kD / 128, kM / 128), 256, 0, stream>>>(Ab, wob, out, kM, kD, kD);
}